// Round 3
// baseline (205.531 us; speedup 1.0000x reference)
//
#include <hip/hip_runtime.h>
#include <hip/hip_bf16.h>
#include <cstdint>

#define BATCH 8192
#define IN_F  4096
#define OUT_F 128
#define KSPLIT 8
#define KSLICE (IN_F / KSPLIT)   // 512
#define NKS    (KSLICE / 32)     // 16 k-steps of 32 per wave
// float32-rounded decay constants (tau_fac=100, tau_dep=200)
#define FD 0.99004983374916811f
#define DD 0.99501247919268232f

typedef __attribute__((ext_vector_type(4))) float f32x4;
typedef __attribute__((ext_vector_type(8))) float f32x8;
typedef __attribute__((ext_vector_type(8))) short bf16x8;

__device__ __forceinline__ unsigned short f2bf(float f){
  union { float f; unsigned u; } v; v.f = f;
  unsigned u = v.u;
  return (unsigned short)((u + 0x7FFFu + ((u >> 16) & 1u)) >> 16);  // RNE
}

// Pre-shuffle weight[128][4096] f32 -> fragment-major bf16 in ws.
// Frag id f = (ks*8 + ct)*64 + l ; lane l holds weight[ct*16+(l&15)][ks*32+(l>>4)*8 + j], j=0..7
__global__ __launch_bounds__(256) void prep_weight_kernel(const float* __restrict__ w,
                                                          unsigned short* __restrict__ wf){
  const int f  = blockIdx.x * 256 + threadIdx.x;   // 0..65535
  const int l  = f & 63;
  const int ct = (f >> 6) & 7;
  const int ks = f >> 9;                           // 0..127
  const int row = ct * 16 + (l & 15);
  const int k   = ks * 32 + ((l >> 4) << 3);
  const f32x4* src = reinterpret_cast<const f32x4*>(w + (size_t)row * IN_F + k);
  f32x4 a = src[0], b = src[1];
  union { bf16x8 v; unsigned short s[8]; } o;
  o.s[0]=f2bf(a[0]); o.s[1]=f2bf(a[1]); o.s[2]=f2bf(a[2]); o.s[3]=f2bf(a[3]);
  o.s[4]=f2bf(b[0]); o.s[5]=f2bf(b[1]); o.s[6]=f2bf(b[2]); o.s[7]=f2bf(b[3]);
  *reinterpret_cast<bf16x8*>(wf + (size_t)f * 8) = o.v;
}

// Fully wave-independent fused kernel: no LDS, no barriers.
// Each wave: 16 rows x 512-K slice. Loads pre/u/x directly in MFMA A-fragment
// layout (lane l -> row l&15, k-chunk (l>>4)*8), does the STP state update in
// registers, packs r=u*x*s to bf16, runs 8 MFMAs per k-step (all col-tiles),
// and atomically accumulates its 16x128 partial into out (pre-zeroed).
template<bool WS>
__global__ __launch_bounds__(256) void stp_fused_kernel(
    const float* __restrict__ pre, const float* __restrict__ uin,
    const float* __restrict__ xin, const float* __restrict__ w,
    const unsigned short* __restrict__ wf,
    float* __restrict__ out, float* __restrict__ un_out, float* __restrict__ xn_out)
{
  const int tid = threadIdx.x;
  const int wv  = tid >> 6;
  const int l   = tid & 63;

  const int kslice  = blockIdx.x & (KSPLIT - 1);
  const int rowBase = (blockIdx.x >> 3) * 64 + wv * 16;   // wave's 16-row group
  const int row     = rowBase + (l & 15);
  const size_t base = (size_t)row * IN_F + kslice * KSLICE + ((l >> 4) << 3);

  f32x4 acc[8];
  #pragma unroll
  for (int ct = 0; ct < 8; ++ct) acc[ct] = (f32x4){0.f,0.f,0.f,0.f};

  // prologue: load k-step 0
  f32x8 sC = *reinterpret_cast<const f32x8*>(pre + base);
  f32x8 uC = *reinterpret_cast<const f32x8*>(uin + base);
  f32x8 xC = *reinterpret_cast<const f32x8*>(xin + base);

  for (int ks = 0; ks < NKS; ++ks){
    const size_t g = base + (size_t)(ks << 5);

    // issue next k-step's loads first — they ride under this iteration's work
    f32x8 sN, uN, xN;
    if (ks + 1 < NKS){
      const size_t gn = base + (size_t)((ks + 1) << 5);
      sN = *reinterpret_cast<const f32x8*>(pre + gn);
      uN = *reinterpret_cast<const f32x8*>(uin + gn);
      xN = *reinterpret_cast<const f32x8*>(xin + gn);
    }

    // ---- elementwise: STP update + A-fragment r = u*x*s in bf16 ----
    f32x8 un, xn;
    union { bf16x8 v; unsigned short s[8]; } af;
    #pragma unroll
    for (int j = 0; j < 8; ++j){
      const float s = sC[j], u = uC[j], x = xC[j];
      af.s[j] = f2bf(u * x * s);
      const float ufd = u * FD;
      const float unj = ufd + 0.5f * (1.0f - ufd) * s;
      un[j] = unj;
      xn[j] = x * DD + (1.0f - x) * DD * (1.0f - s * unj);
    }
    *reinterpret_cast<f32x8*>(un_out + g) = un;
    *reinterpret_cast<f32x8*>(xn_out + g) = xn;

    // ---- MFMA: 8 col-tiles, B-fragments from L2-resident wf ----
    const int gks = kslice * NKS + ks;            // global k-step 0..127
    if (WS){
      const bf16x8* wfp = reinterpret_cast<const bf16x8*>(wf);
      #pragma unroll
      for (int ct = 0; ct < 8; ++ct){
        bf16x8 bf = wfp[(size_t)((gks * 8 + ct) << 6) + l];
        acc[ct] = __builtin_amdgcn_mfma_f32_16x16x32_bf16(af.v, bf, acc[ct], 0, 0, 0);
      }
    } else {
      const int kg = gks * 32 + ((l >> 4) << 3);
      #pragma unroll
      for (int ct = 0; ct < 8; ++ct){
        const int r0 = ct * 16 + (l & 15);
        const f32x4* p = reinterpret_cast<const f32x4*>(w + (size_t)r0 * IN_F + kg);
        f32x4 a = p[0], b = p[1];
        union { bf16x8 v; unsigned short s[8]; } t;
        t.s[0]=f2bf(a[0]); t.s[1]=f2bf(a[1]); t.s[2]=f2bf(a[2]); t.s[3]=f2bf(a[3]);
        t.s[4]=f2bf(b[0]); t.s[5]=f2bf(b[1]); t.s[6]=f2bf(b[2]); t.s[7]=f2bf(b[3]);
        acc[ct] = __builtin_amdgcn_mfma_f32_16x16x32_bf16(af.v, t.v, acc[ct], 0, 0, 0);
      }
    }

    sC = sN; uC = uN; xC = xN;
  }

  // ---- epilogue: C/D layout col=lane&15, row=(lane>>4)*4+reg; K-split partials
  // combined with f32 HW atomics (out pre-zeroed by hipMemsetAsync) ----
  const int col0 = l & 15;
  const int r0   = rowBase + ((l >> 4) << 2);
  #pragma unroll
  for (int ct = 0; ct < 8; ++ct){
    #pragma unroll
    for (int rg = 0; rg < 4; ++rg){
      unsafeAtomicAdd(&out[(size_t)(r0 + rg) * OUT_F + ct * 16 + col0], acc[ct][rg]);
    }
  }
}

extern "C" void kernel_launch(void* const* d_in, const int* in_sizes, int n_in,
                              void* d_out, int out_size, void* d_ws, size_t ws_size,
                              hipStream_t stream){
  const float* pre = (const float*)d_in[0];
  const float* w   = (const float*)d_in[1];
  const float* u   = (const float*)d_in[2];
  const float* x   = (const float*)d_in[3];
  float* out    = (float*)d_out;
  float* un_out = out + (size_t)BATCH * OUT_F;
  float* xn_out = un_out + (size_t)BATCH * IN_F;
  unsigned short* wf = (unsigned short*)d_ws;

  // zero the GEMM output region (atomic accumulation target); un/xn are
  // fully overwritten so no init needed there
  hipMemsetAsync(out, 0, (size_t)BATCH * OUT_F * sizeof(float), stream);

  const bool use_ws = (ws_size >= (size_t)(1 << 20));
  const int grid = (BATCH / 64) * KSPLIT;   // 1024 blocks, 4 waves each
  if (use_ws){
    prep_weight_kernel<<<256, 256, 0, stream>>>(w, wf);
    stp_fused_kernel<true><<<grid, 256, 0, stream>>>(pre, u, x, w, wf, out, un_out, xn_out);
  } else {
    stp_fused_kernel<false><<<grid, 256, 0, stream>>>(pre, u, x, w, nullptr, out, un_out, xn_out);
  }
}

// Round 4
// 187.693 us; speedup vs baseline: 1.0950x; 1.0950x over previous
//
#include <hip/hip_runtime.h>
#include <hip/hip_bf16.h>
#include <cstdint>

#define BATCH 8192
#define IN_F  4096
#define OUT_F 128
#define KSPLIT 16
#define KSLICE (IN_F / KSPLIT)   // 256
#define NKS    (KSLICE / 32)     // 8 k-steps of 32 per wave
// float32-rounded decay constants (tau_fac=100, tau_dep=200)
#define FD 0.99004983374916811f
#define DD 0.99501247919268232f

typedef __attribute__((ext_vector_type(4))) float f32x4;
typedef __attribute__((ext_vector_type(8))) float f32x8;
typedef __attribute__((ext_vector_type(8))) short bf16x8;

__device__ __forceinline__ unsigned short f2bf(float f){
  union { float f; unsigned u; } v; v.f = f;
  unsigned u = v.u;
  return (unsigned short)((u + 0x7FFFu + ((u >> 16) & 1u)) >> 16);  // RNE
}

// Pre-shuffle weight[128][4096] f32 -> fragment-major bf16 in ws.
// Frag id f = (ks*8 + ct)*64 + l ; lane l holds weight[ct*16+(l&15)][ks*32+(l>>4)*8 + j], j=0..7
__global__ __launch_bounds__(256) void prep_weight_kernel(const float* __restrict__ w,
                                                          unsigned short* __restrict__ wf){
  const int f  = blockIdx.x * 256 + threadIdx.x;   // 0..65535
  const int l  = f & 63;
  const int ct = (f >> 6) & 7;
  const int ks = f >> 9;                           // 0..127
  const int row = ct * 16 + (l & 15);
  const int k   = ks * 32 + ((l >> 4) << 3);
  const f32x4* src = reinterpret_cast<const f32x4*>(w + (size_t)row * IN_F + k);
  f32x4 a = src[0], b = src[1];
  union { bf16x8 v; unsigned short s[8]; } o;
  o.s[0]=f2bf(a[0]); o.s[1]=f2bf(a[1]); o.s[2]=f2bf(a[2]); o.s[3]=f2bf(a[3]);
  o.s[4]=f2bf(b[0]); o.s[5]=f2bf(b[1]); o.s[6]=f2bf(b[2]); o.s[7]=f2bf(b[3]);
  *reinterpret_cast<bf16x8*>(wf + (size_t)f * 8) = o.v;
}

// Wave-independent fused kernel: no LDS, no barriers, no vmcnt(0) drains.
// Each wave: 16 rows x 256-K slice (KSPLIT=16 -> 2048 blocks -> 8 blocks/CU).
// Per k-step iteration order (ILP): issue B-frag loads -> issue next A loads
// -> elementwise STP (covers B L2 latency) -> stores -> 8 MFMAs.
template<bool WS>
__global__ __launch_bounds__(256, 4) void stp_fused_kernel(
    const float* __restrict__ pre, const float* __restrict__ uin,
    const float* __restrict__ xin, const float* __restrict__ w,
    const unsigned short* __restrict__ wf,
    float* __restrict__ out, float* __restrict__ un_out, float* __restrict__ xn_out)
{
  const int tid = threadIdx.x;
  const int wv  = tid >> 6;
  const int l   = tid & 63;

  const int kslice  = blockIdx.x & (KSPLIT - 1);
  const int rowBase = (blockIdx.x >> 4) * 64 + wv * 16;   // wave's 16-row group
  const int row     = rowBase + (l & 15);
  const size_t base = (size_t)row * IN_F + kslice * KSLICE + ((l >> 4) << 3);

  f32x4 acc[8];
  #pragma unroll
  for (int ct = 0; ct < 8; ++ct) acc[ct] = (f32x4){0.f,0.f,0.f,0.f};

  // prologue: load k-step 0's A inputs
  f32x8 sC = *reinterpret_cast<const f32x8*>(pre + base);
  f32x8 uC = *reinterpret_cast<const f32x8*>(uin + base);
  f32x8 xC = *reinterpret_cast<const f32x8*>(xin + base);

  for (int ks = 0; ks < NKS; ++ks){
    const size_t g   = base + (size_t)(ks << 5);
    const int    gks = kslice * NKS + ks;          // global k-step 0..127

    // ---- issue this iter's B-fragment loads (independent, L2-resident) ----
    bf16x8 bf[8];
    if (WS){
      const bf16x8* wfp = reinterpret_cast<const bf16x8*>(wf);
      #pragma unroll
      for (int ct = 0; ct < 8; ++ct)
        bf[ct] = wfp[(size_t)((gks * 8 + ct) << 6) + l];
    } else {
      const int kg = gks * 32 + ((l >> 4) << 3);
      #pragma unroll
      for (int ct = 0; ct < 8; ++ct){
        const int r0 = ct * 16 + (l & 15);
        const f32x4* p = reinterpret_cast<const f32x4*>(w + (size_t)r0 * IN_F + kg);
        f32x4 a = p[0], b = p[1];
        union { bf16x8 v; unsigned short s[8]; } t;
        t.s[0]=f2bf(a[0]); t.s[1]=f2bf(a[1]); t.s[2]=f2bf(a[2]); t.s[3]=f2bf(a[3]);
        t.s[4]=f2bf(b[0]); t.s[5]=f2bf(b[1]); t.s[6]=f2bf(b[2]); t.s[7]=f2bf(b[3]);
        bf[ct] = t.v;
      }
    }

    // ---- issue next iter's A loads (one full iteration of slack) ----
    f32x8 sN, uN, xN;
    if (ks + 1 < NKS){
      const size_t gn = base + (size_t)((ks + 1) << 5);
      sN = *reinterpret_cast<const f32x8*>(pre + gn);
      uN = *reinterpret_cast<const f32x8*>(uin + gn);
      xN = *reinterpret_cast<const f32x8*>(xin + gn);
    }

    // ---- elementwise: STP update + A-fragment r = u*x*s in bf16 ----
    f32x8 un, xn;
    union { bf16x8 v; unsigned short s[8]; } af;
    #pragma unroll
    for (int j = 0; j < 8; ++j){
      const float s = sC[j], u = uC[j], x = xC[j];
      af.s[j] = f2bf(u * x * s);
      const float ufd = u * FD;
      const float unj = ufd + 0.5f * (1.0f - ufd) * s;
      un[j] = unj;
      xn[j] = x * DD + (1.0f - x) * DD * (1.0f - s * unj);
    }
    *reinterpret_cast<f32x8*>(un_out + g) = un;
    *reinterpret_cast<f32x8*>(xn_out + g) = xn;

    // ---- MFMA: 8 col-tiles ----
    #pragma unroll
    for (int ct = 0; ct < 8; ++ct)
      acc[ct] = __builtin_amdgcn_mfma_f32_16x16x32_bf16(af.v, bf[ct], acc[ct], 0, 0, 0);

    sC = sN; uC = uN; xC = xN;
  }

  // ---- epilogue: C/D layout col=lane&15, row=(lane>>4)*4+reg; K-split partials
  // combined with f32 HW atomics (out pre-zeroed by hipMemsetAsync) ----
  const int col0 = l & 15;
  const int r0   = rowBase + ((l >> 4) << 2);
  #pragma unroll
  for (int ct = 0; ct < 8; ++ct){
    #pragma unroll
    for (int rg = 0; rg < 4; ++rg){
      unsafeAtomicAdd(&out[(size_t)(r0 + rg) * OUT_F + ct * 16 + col0], acc[ct][rg]);
    }
  }
}

extern "C" void kernel_launch(void* const* d_in, const int* in_sizes, int n_in,
                              void* d_out, int out_size, void* d_ws, size_t ws_size,
                              hipStream_t stream){
  const float* pre = (const float*)d_in[0];
  const float* w   = (const float*)d_in[1];
  const float* u   = (const float*)d_in[2];
  const float* x   = (const float*)d_in[3];
  float* out    = (float*)d_out;
  float* un_out = out + (size_t)BATCH * OUT_F;
  float* xn_out = un_out + (size_t)BATCH * IN_F;
  unsigned short* wf = (unsigned short*)d_ws;

  // zero the GEMM output region (atomic accumulation target); un/xn are
  // fully overwritten so no init needed there
  hipMemsetAsync(out, 0, (size_t)BATCH * OUT_F * sizeof(float), stream);

  const bool use_ws = (ws_size >= (size_t)(1 << 20));
  const int grid = (BATCH / 64) * KSPLIT;   // 2048 blocks, 4 waves each
  if (use_ws){
    prep_weight_kernel<<<256, 256, 0, stream>>>(w, wf);
    stp_fused_kernel<true><<<grid, 256, 0, stream>>>(pre, u, x, w, wf, out, un_out, xn_out);
  } else {
    stp_fused_kernel<false><<<grid, 256, 0, stream>>>(pre, u, x, w, nullptr, out, un_out, xn_out);
  }
}